// Round 1
// baseline (302.866 us; speedup 1.0000x reference)
//
#include <hip/hip_runtime.h>
#include <hip/hip_bf16.h>
#include <cstdint>
#include <cstddef>

#define D_MODEL 1024
#define NHEADS  16
#define HDIM    64
#define HALFW   32
#define BATCH   4
#define SEQ     4096
#define MROWS   (BATCH*SEQ)

typedef __attribute__((ext_vector_type(8))) short        bf16x8;
typedef __attribute__((ext_vector_type(4))) float        f32x4;
typedef __attribute__((ext_vector_type(4))) unsigned int u32x4;

typedef const __attribute__((address_space(1))) void gvoid_t;
typedef __attribute__((address_space(3))) void       lvoid_t;

__device__ __forceinline__ unsigned short f2bf(float f) {
    unsigned int u = __float_as_uint(f);
    u += 0x7fffu + ((u >> 16) & 1u);   // RNE
    return (unsigned short)(u >> 16);
}

// ---------------- f32 -> bf16 conversion (vectorized, 8 elems/thread) ----------
__global__ __launch_bounds__(256)
void cvt_f32_bf16(const float* __restrict__ src, unsigned short* __restrict__ dst, int n8) {
    int i = blockIdx.x * 256 + threadIdx.x;
    if (i >= n8) return;
    float4 a = *(const float4*)(src + (size_t)i * 8);
    float4 b = *(const float4*)(src + (size_t)i * 8 + 4);
    u32x4 o;
    o[0] = (unsigned)f2bf(a.x) | ((unsigned)f2bf(a.y) << 16);
    o[1] = (unsigned)f2bf(a.z) | ((unsigned)f2bf(a.w) << 16);
    o[2] = (unsigned)f2bf(b.x) | ((unsigned)f2bf(b.y) << 16);
    o[3] = (unsigned)f2bf(b.z) | ((unsigned)f2bf(b.w) << 16);
    *(u32x4*)(dst + (size_t)i * 8) = o;
}

// ---------------- bf16 GEMM, B^T layout: out[m,n] = sum_k A[m,k]*W[n,k] + bias[n]
// 128x128 tile, BK=32, 4 waves (2x2), global_load_lds staging, 16x16x32 MFMA.
template <int F32OUT>
__global__ __launch_bounds__(256)
void gemm_bt(const unsigned short* __restrict__ A,
             const unsigned short* __restrict__ W,
             const float* __restrict__ bias,
             unsigned short* __restrict__ obf,
             float* __restrict__ of32)
{
    constexpr int K = 1024, N = 1024;
    __shared__ unsigned short As[128 * 32];
    __shared__ unsigned short Bs[128 * 32];
    const int tid  = threadIdx.x;
    const int wave = tid >> 6, lane = tid & 63;
    const int wr = wave >> 1, wc = wave & 1;
    const int bm = blockIdx.x * 128, bn = blockIdx.y * 128;

    f32x4 acc[4][4];
    #pragma unroll
    for (int m = 0; m < 4; ++m)
        #pragma unroll
        for (int n = 0; n < 4; ++n)
            #pragma unroll
            for (int j = 0; j < 4; ++j) acc[m][n][j] = 0.0f;

    const int srow = wave * 32 + (lane >> 2);   // staging row (per chunk r add 16)
    const int scol = (lane & 3) * 8;            // staging col (elems)

    for (int k0 = 0; k0 < K; k0 += 32) {
        #pragma unroll
        for (int r = 0; r < 2; ++r) {
            const int row = srow + r * 16;
            __builtin_amdgcn_global_load_lds(
                (gvoid_t*)(A + (size_t)(bm + row) * K + k0 + scol),
                (lvoid_t*)(As + (wave * 2 + r) * 512), 16, 0, 0);
            __builtin_amdgcn_global_load_lds(
                (gvoid_t*)(W + (size_t)(bn + row) * K + k0 + scol),
                (lvoid_t*)(Bs + (wave * 2 + r) * 512), 16, 0, 0);
        }
        __syncthreads();   // drains vmcnt (compiler emits waitcnt before barrier)

        bf16x8 af[4], bw[4];
        #pragma unroll
        for (int m = 0; m < 4; ++m)
            af[m] = *(const bf16x8*)(As + (wr * 64 + m * 16 + (lane & 15)) * 32 + (lane >> 4) * 8);
        #pragma unroll
        for (int n = 0; n < 4; ++n)
            bw[n] = *(const bf16x8*)(Bs + (wc * 64 + n * 16 + (lane & 15)) * 32 + (lane >> 4) * 8);
        #pragma unroll
        for (int m = 0; m < 4; ++m)
            #pragma unroll
            for (int n = 0; n < 4; ++n)
                acc[m][n] = __builtin_amdgcn_mfma_f32_16x16x32_bf16(af[m], bw[n], acc[m][n], 0, 0, 0);
        __syncthreads();
    }

    #pragma unroll
    for (int n = 0; n < 4; ++n) {
        const int col = bn + wc * 64 + n * 16 + (lane & 15);
        const float bv = bias[col];
        #pragma unroll
        for (int m = 0; m < 4; ++m) {
            #pragma unroll
            for (int j = 0; j < 4; ++j) {
                const int row = bm + wr * 64 + m * 16 + (lane >> 4) * 4 + j;
                const float v = acc[m][n][j] + bv;
                if (F32OUT) of32[(size_t)row * N + col] = v;
                else        obf[(size_t)row * N + col]  = f2bf(v);
            }
        }
    }
}

// ---------------- banded attention: one block per (b, h, 64-query tile) --------
// keys in [qbase-32, qbase+96), mask |kpos-qpos|<=32 && 0<=kpos<SEQ
__global__ __launch_bounds__(256)
void attn_band(const unsigned short* __restrict__ Q,
               const unsigned short* __restrict__ Kk,
               const unsigned short* __restrict__ V,
               unsigned short* __restrict__ Ctx)
{
    __shared__ unsigned short Qs[64 * 64];    // [q][hd]
    __shared__ unsigned short Ks[128 * 64];   // [key][hd]
    __shared__ unsigned short Vt[64 * 128];   // [hd][key]  (transposed for B-frags)
    __shared__ unsigned short Ps[64 * 128];   // [q][key] bf16 probs

    const int qt = blockIdx.x, h = blockIdx.y, b = blockIdx.z;
    const int qbase  = qt * 64;
    const int kstart = qbase - HALFW;
    const int tid = threadIdx.x, wave = tid >> 6, lane = tid & 63;

    const size_t base = (size_t)b * SEQ * D_MODEL + (size_t)h * HDIM;
    const unsigned short* Qb = Q  + base;
    const unsigned short* Kb = Kk + base;
    const unsigned short* Vb = V  + base;
    unsigned short*       Cb = Ctx + base;

    // stage Q (64x64): 512 16B-chunks
    for (int c = tid; c < 512; c += 256) {
        const int row = c >> 3, col = (c & 7) * 8;
        *(u32x4*)(Qs + row * 64 + col) =
            *(const u32x4*)(Qb + (size_t)(qbase + row) * D_MODEL + col);
    }
    // stage K row-major + V transposed, zero-fill out-of-range keys
    for (int c = tid; c < 1024; c += 256) {
        const int krow = c >> 3, col = (c & 7) * 8;
        const int kpos = kstart + krow;
        u32x4 kv, vv;
        if (kpos >= 0 && kpos < SEQ) {
            kv = *(const u32x4*)(Kb + (size_t)kpos * D_MODEL + col);
            vv = *(const u32x4*)(Vb + (size_t)kpos * D_MODEL + col);
        } else {
            #pragma unroll
            for (int j = 0; j < 4; ++j) { kv[j] = 0u; vv[j] = 0u; }
        }
        *(u32x4*)(Ks + krow * 64 + col) = kv;
        #pragma unroll
        for (int j = 0; j < 8; ++j)
            Vt[(col + j) * 128 + krow] =
                (unsigned short)((vv[j >> 1] >> ((j & 1) * 16)) & 0xffffu);
    }
    __syncthreads();

    // QK^T: wave handles queries [wave*16, wave*16+16) x 128 keys (8 col-tiles)
    f32x4 sc[8];
    #pragma unroll
    for (int c = 0; c < 8; ++c)
        #pragma unroll
        for (int j = 0; j < 4; ++j) sc[c][j] = 0.0f;

    bf16x8 aq[2];
    #pragma unroll
    for (int kc = 0; kc < 2; ++kc)
        aq[kc] = *(const bf16x8*)(Qs + (wave * 16 + (lane & 15)) * 64 + kc * 32 + (lane >> 4) * 8);
    #pragma unroll
    for (int c = 0; c < 8; ++c) {
        #pragma unroll
        for (int kc = 0; kc < 2; ++kc) {
            bf16x8 bk_ = *(const bf16x8*)(Ks + (c * 16 + (lane & 15)) * 64 + kc * 32 + (lane >> 4) * 8);
            sc[c] = __builtin_amdgcn_mfma_f32_16x16x32_bf16(aq[kc], bk_, sc[c], 0, 0, 0);
        }
    }

    // masked softmax; acc layout: col = lane&15 (key), row = (lane>>4)*4 + j (query)
    const int grp = lane >> 4, colk = lane & 15;
    float rowmax[4] = {-1e30f, -1e30f, -1e30f, -1e30f};
    #pragma unroll
    for (int c = 0; c < 8; ++c) {
        const int kpos = kstart + c * 16 + colk;
        #pragma unroll
        for (int j = 0; j < 4; ++j) {
            const int qpos = qbase + wave * 16 + grp * 4 + j;
            const int rel = kpos - qpos;
            const bool valid = (kpos >= 0) && (kpos < SEQ) && (rel >= -HALFW) && (rel <= HALFW);
            const float v = valid ? sc[c][j] * 0.125f : -1e30f;
            sc[c][j] = v;
            rowmax[j] = fmaxf(rowmax[j], v);
        }
    }
    #pragma unroll
    for (int j = 0; j < 4; ++j)
        #pragma unroll
        for (int m = 1; m < 16; m <<= 1)
            rowmax[j] = fmaxf(rowmax[j], __shfl_xor(rowmax[j], m, 64));

    float rowsum[4] = {0.f, 0.f, 0.f, 0.f};
    #pragma unroll
    for (int c = 0; c < 8; ++c)
        #pragma unroll
        for (int j = 0; j < 4; ++j) {
            const float p = __expf(sc[c][j] - rowmax[j]);
            sc[c][j] = p;
            rowsum[j] += p;
        }
    #pragma unroll
    for (int j = 0; j < 4; ++j)
        #pragma unroll
        for (int m = 1; m < 16; m <<= 1)
            rowsum[j] += __shfl_xor(rowsum[j], m, 64);

    // write P (bf16) to LDS for A-fragment re-layout
    #pragma unroll
    for (int c = 0; c < 8; ++c)
        #pragma unroll
        for (int j = 0; j < 4; ++j)
            Ps[(wave * 16 + grp * 4 + j) * 128 + c * 16 + colk] = f2bf(sc[c][j]);
    __syncthreads();

    // PV: P[16x128] @ V[128x64]
    f32x4 o[4];
    #pragma unroll
    for (int n = 0; n < 4; ++n)
        #pragma unroll
        for (int j = 0; j < 4; ++j) o[n][j] = 0.0f;
    #pragma unroll
    for (int kc = 0; kc < 4; ++kc) {
        bf16x8 pa = *(const bf16x8*)(Ps + (wave * 16 + (lane & 15)) * 128 + kc * 32 + (lane >> 4) * 8);
        #pragma unroll
        for (int n = 0; n < 4; ++n) {
            bf16x8 bv_ = *(const bf16x8*)(Vt + (n * 16 + (lane & 15)) * 128 + kc * 32 + (lane >> 4) * 8);
            o[n] = __builtin_amdgcn_mfma_f32_16x16x32_bf16(pa, bv_, o[n], 0, 0, 0);
        }
    }

    float rinv[4];
    #pragma unroll
    for (int j = 0; j < 4; ++j) rinv[j] = 1.0f / rowsum[j];
    #pragma unroll
    for (int n = 0; n < 4; ++n)
        #pragma unroll
        for (int j = 0; j < 4; ++j) {
            const int q = qbase + wave * 16 + grp * 4 + j;
            Cb[(size_t)q * D_MODEL + n * 16 + colk] = f2bf(o[n][j] * rinv[j]);
        }
}

// ------------------------------------------------------------------------------
extern "C" void kernel_launch(void* const* d_in, const int* in_sizes, int n_in,
                              void* d_out, int out_size, void* d_ws, size_t ws_size,
                              hipStream_t stream)
{
    (void)in_sizes; (void)n_in; (void)out_size; (void)ws_size;
    const float* x  = (const float*)d_in[0];
    const float* Wq = (const float*)d_in[1];
    const float* bq = (const float*)d_in[2];
    const float* Wk = (const float*)d_in[3];
    const float* bk = (const float*)d_in[4];
    const float* Wv = (const float*)d_in[5];
    const float* bv = (const float*)d_in[6];
    const float* Wo = (const float*)d_in[7];
    const float* bo = (const float*)d_in[8];
    float* out = (float*)d_out;

    char* ws = (char*)d_ws;
    unsigned short* xb  = (unsigned short*)ws;                    // 16.8M elems (33.5MB)
    unsigned short* wqb = (unsigned short*)(ws + 33554432);
    unsigned short* wkb = wqb + 1048576;
    unsigned short* wvb = wkb + 1048576;
    unsigned short* wob = wvb + 1048576;
    unsigned short* qb  = wob + 1048576;
    unsigned short* kb  = qb + (size_t)MROWS * D_MODEL;
    unsigned short* vb  = kb + (size_t)MROWS * D_MODEL;
    unsigned short* ctxb = xb;   // alias: x no longer needed after QKV GEMMs

    // conversions
    cvt_f32_bf16<<<dim3(MROWS * D_MODEL / 8 / 256), 256, 0, stream>>>(x,  xb,  MROWS * D_MODEL / 8);
    cvt_f32_bf16<<<dim3(D_MODEL * D_MODEL / 8 / 256), 256, 0, stream>>>(Wq, wqb, D_MODEL * D_MODEL / 8);
    cvt_f32_bf16<<<dim3(D_MODEL * D_MODEL / 8 / 256), 256, 0, stream>>>(Wk, wkb, D_MODEL * D_MODEL / 8);
    cvt_f32_bf16<<<dim3(D_MODEL * D_MODEL / 8 / 256), 256, 0, stream>>>(Wv, wvb, D_MODEL * D_MODEL / 8);
    cvt_f32_bf16<<<dim3(D_MODEL * D_MODEL / 8 / 256), 256, 0, stream>>>(Wo, wob, D_MODEL * D_MODEL / 8);

    dim3 g(MROWS / 128, D_MODEL / 128), blk(256);
    gemm_bt<0><<<g, blk, 0, stream>>>(xb, wqb, bq, qb, nullptr);
    gemm_bt<0><<<g, blk, 0, stream>>>(xb, wkb, bk, kb, nullptr);
    gemm_bt<0><<<g, blk, 0, stream>>>(xb, wvb, bv, vb, nullptr);

    attn_band<<<dim3(SEQ / 64, NHEADS, BATCH), 256, 0, stream>>>(qb, kb, vb, ctxb);

    gemm_bt<1><<<g, blk, 0, stream>>>(ctxb, wob, bo, nullptr, out);
}

// Round 3
// 256.029 us; speedup vs baseline: 1.1829x; 1.1829x over previous
//
#include <hip/hip_runtime.h>
#include <hip/hip_bf16.h>
#include <cstdint>
#include <cstddef>

#define D_MODEL 1024
#define NHEADS  16
#define HDIM    64
#define HALFW   32
#define BATCH   4
#define SEQ     4096
#define MROWS   (BATCH*SEQ)

typedef __attribute__((ext_vector_type(8))) short        bf16x8;
typedef __attribute__((ext_vector_type(4))) float        f32x4;
typedef __attribute__((ext_vector_type(4))) unsigned int u32x4;

typedef const __attribute__((address_space(1))) void gvoid_t;
typedef __attribute__((address_space(3))) void       lvoid_t;

__device__ __forceinline__ unsigned short f2bf(float f) {
    unsigned int u = __float_as_uint(f);
    u += 0x7fffu + ((u >> 16) & 1u);   // RNE
    return (unsigned short)(u >> 16);
}

// XOR swizzle for row-major [R][128] bf16 LDS tiles (256B rows).
// byte ^= ((row ^ row>>3)&7)<<4 : spreads banks for both d-indexed reads
// (b128 column-slice) and k-indexed paired writes. Involution: same on R/W.
__device__ __forceinline__ int vswz(int row, int bytecol) {
    return (row * 256 + bytecol) ^ (((row ^ (row >> 3)) & 7) << 4);
}

// ---------------- f32 -> bf16 conversion (vectorized, 8 elems/thread) ----------
__global__ __launch_bounds__(256)
void cvt_f32_bf16(const float* __restrict__ src, unsigned short* __restrict__ dst, int n8) {
    int i = blockIdx.x * 256 + threadIdx.x;
    if (i >= n8) return;
    float4 a = *(const float4*)(src + (size_t)i * 8);
    float4 b = *(const float4*)(src + (size_t)i * 8 + 4);
    u32x4 o;
    o[0] = (unsigned)f2bf(a.x) | ((unsigned)f2bf(a.y) << 16);
    o[1] = (unsigned)f2bf(a.z) | ((unsigned)f2bf(a.w) << 16);
    o[2] = (unsigned)f2bf(b.x) | ((unsigned)f2bf(b.y) << 16);
    o[3] = (unsigned)f2bf(b.z) | ((unsigned)f2bf(b.w) << 16);
    *(u32x4*)(dst + (size_t)i * 8) = o;
}

// 4 weight matrices in one launch (blockIdx.y selects matrix)
__global__ __launch_bounds__(256)
void cvt4_f32_bf16(const float* __restrict__ s0, const float* __restrict__ s1,
                   const float* __restrict__ s2, const float* __restrict__ s3,
                   unsigned short* __restrict__ d0, unsigned short* __restrict__ d1,
                   unsigned short* __restrict__ d2, unsigned short* __restrict__ d3, int n8) {
    int i = blockIdx.x * 256 + threadIdx.x;
    if (i >= n8) return;
    const float* src = blockIdx.y == 0 ? s0 : blockIdx.y == 1 ? s1 : blockIdx.y == 2 ? s2 : s3;
    unsigned short* dst = blockIdx.y == 0 ? d0 : blockIdx.y == 1 ? d1 : blockIdx.y == 2 ? d2 : d3;
    float4 a = *(const float4*)(src + (size_t)i * 8);
    float4 b = *(const float4*)(src + (size_t)i * 8 + 4);
    u32x4 o;
    o[0] = (unsigned)f2bf(a.x) | ((unsigned)f2bf(a.y) << 16);
    o[1] = (unsigned)f2bf(a.z) | ((unsigned)f2bf(a.w) << 16);
    o[2] = (unsigned)f2bf(b.x) | ((unsigned)f2bf(b.y) << 16);
    o[3] = (unsigned)f2bf(b.z) | ((unsigned)f2bf(b.w) << 16);
    *(u32x4*)(dst + (size_t)i * 8) = o;
}

// ---------------- bf16 GEMM, B^T layout, fused multi-output ------------------
// out[m,n] = sum_k A[m,k]*W[n,k] + bias[n].  CB col-blocks of 128 (8 per output
// set). XCD-chunked swizzle: each XCD owns 16 contiguous A-rows x all cols,
// in sub-chunks of 8 rows (A 2MB + B panels ~1.5MB resident in 4MB L2).
template <int CB, int F32OUT>
__global__ __launch_bounds__(256)
void gemm_fused(const unsigned short* __restrict__ A,
                const unsigned short* __restrict__ W0,
                const unsigned short* __restrict__ W1,
                const unsigned short* __restrict__ W2,
                const float* __restrict__ b0, const float* __restrict__ b1,
                const float* __restrict__ b2,
                unsigned short* __restrict__ o0, unsigned short* __restrict__ o1,
                unsigned short* __restrict__ o2, float* __restrict__ of32)
{
    constexpr int K = 1024, N = 1024;
    __shared__ unsigned short As[128 * 32];
    __shared__ unsigned short Bs[128 * 32];
    const int tid  = threadIdx.x;
    const int wave = tid >> 6, lane = tid & 63;
    const int wr = wave >> 1, wc = wave & 1;

    // bijective XCD-aware swizzle (grid = 128*CB blocks, 128*CB % 8 == 0)
    const int bid = blockIdx.x;
    const int x   = bid & 7;              // XCD slot
    const int lw  = bid >> 3;             // [0, 16*CB)
    const int sub = lw / (8 * CB);
    const int l2  = lw % (8 * CB);
    const int cb  = l2 >> 3;              // col-block [0, CB)
    const int rl  = l2 & 7;
    const int r   = x * 16 + sub * 8 + rl;
    const int which = cb >> 3;
    const int bm = r * 128, bn = (cb & 7) * 128;

    const unsigned short* W = which == 0 ? W0 : (which == 1 ? W1 : W2);
    const float* bias       = which == 0 ? b0 : (which == 1 ? b1 : b2);
    unsigned short* obf     = which == 0 ? o0 : (which == 1 ? o1 : o2);

    f32x4 acc[4][4];
    #pragma unroll
    for (int m = 0; m < 4; ++m)
        #pragma unroll
        for (int n = 0; n < 4; ++n)
            #pragma unroll
            for (int j = 0; j < 4; ++j) acc[m][n][j] = 0.0f;

    const int srow = wave * 32 + (lane >> 2);
    const int scol = (lane & 3) * 8;

    for (int k0 = 0; k0 < K; k0 += 32) {
        #pragma unroll
        for (int rr = 0; rr < 2; ++rr) {
            const int row = srow + rr * 16;
            __builtin_amdgcn_global_load_lds(
                (gvoid_t*)(A + (size_t)(bm + row) * K + k0 + scol),
                (lvoid_t*)(As + (wave * 2 + rr) * 512), 16, 0, 0);
            __builtin_amdgcn_global_load_lds(
                (gvoid_t*)(W + (size_t)(bn + row) * K + k0 + scol),
                (lvoid_t*)(Bs + (wave * 2 + rr) * 512), 16, 0, 0);
        }
        __syncthreads();

        bf16x8 af[4], bw[4];
        #pragma unroll
        for (int m = 0; m < 4; ++m)
            af[m] = *(const bf16x8*)(As + (wr * 64 + m * 16 + (lane & 15)) * 32 + (lane >> 4) * 8);
        #pragma unroll
        for (int n = 0; n < 4; ++n)
            bw[n] = *(const bf16x8*)(Bs + (wc * 64 + n * 16 + (lane & 15)) * 32 + (lane >> 4) * 8);
        #pragma unroll
        for (int m = 0; m < 4; ++m)
            #pragma unroll
            for (int n = 0; n < 4; ++n)
                acc[m][n] = __builtin_amdgcn_mfma_f32_16x16x32_bf16(af[m], bw[n], acc[m][n], 0, 0, 0);
        __syncthreads();
    }

    #pragma unroll
    for (int n = 0; n < 4; ++n) {
        const int col = bn + wc * 64 + n * 16 + (lane & 15);
        const float bv = bias[col];
        #pragma unroll
        for (int m = 0; m < 4; ++m) {
            #pragma unroll
            for (int j = 0; j < 4; ++j) {
                const int row = bm + wr * 64 + m * 16 + (lane >> 4) * 4 + j;
                const float v = acc[m][n][j] + bv;
                if (F32OUT) of32[(size_t)row * N + col] = v;
                else        obf[(size_t)row * N + col]  = f2bf(v);
            }
        }
    }
}

// ---------------- banded attention: one block per (b, h, 64-query tile) --------
// keys in [qbase-32, qbase+96), mask |kpos-qpos|<=32 && 0<=kpos<SEQ
__global__ __launch_bounds__(256)
void attn_band(const unsigned short* __restrict__ Q,
               const unsigned short* __restrict__ Kk,
               const unsigned short* __restrict__ V,
               unsigned short* __restrict__ Ctx)
{
    __shared__ unsigned short Qs[64 * 72];    // [q][hd], pad 64->72
    __shared__ unsigned short Ks[128 * 72];   // [key][hd], pad
    __shared__ unsigned short Vt[64 * 128];   // [hd][key], XOR-swizzled
    __shared__ unsigned short Ps[64 * 128];   // [q][key],  XOR-swizzled

    const int qt = blockIdx.x, h = blockIdx.y, b = blockIdx.z;
    const int qbase  = qt * 64;
    const int kstart = qbase - HALFW;
    const int tid = threadIdx.x, wave = tid >> 6, lane = tid & 63;

    const size_t base = (size_t)b * SEQ * D_MODEL + (size_t)h * HDIM;
    const unsigned short* Qb = Q  + base;
    const unsigned short* Kb = Kk + base;
    const unsigned short* Vb = V  + base;
    unsigned short*       Cb = Ctx + base;

    // stage Q (64x64) into padded rows
    for (int c = tid; c < 512; c += 256) {
        const int row = c >> 3, col = (c & 7) * 8;
        *(u32x4*)(Qs + row * 72 + col) =
            *(const u32x4*)(Qb + (size_t)(qbase + row) * D_MODEL + col);
    }
    // stage K row-major (padded), zero-fill out-of-range keys
    for (int c = tid; c < 1024; c += 256) {
        const int krow = c >> 3, col = (c & 7) * 8;
        const int kpos = kstart + krow;
        u32x4 kv;
        if (kpos >= 0 && kpos < SEQ) {
            kv = *(const u32x4*)(Kb + (size_t)kpos * D_MODEL + col);
        } else {
            for (int j = 0; j < 4; ++j) kv[j] = 0u;
        }
        *(u32x4*)(Ks + krow * 72 + col) = kv;
    }
    // stage V transposed: key-PAIRS packed as u32, swizzled rows
    for (int c = tid; c < 512; c += 256) {
        const int p = c >> 3, dch = c & 7;      // keys 2p,2p+1 ; d-chunk
        const int k0 = kstart + 2 * p, k1 = k0 + 1;
        u32x4 v0, v1;
        if (k0 >= 0 && k0 < SEQ) {
            v0 = *(const u32x4*)(Vb + (size_t)k0 * D_MODEL + dch * 8);
        } else {
            for (int j = 0; j < 4; ++j) v0[j] = 0u;
        }
        if (k1 >= 0 && k1 < SEQ) {
            v1 = *(const u32x4*)(Vb + (size_t)k1 * D_MODEL + dch * 8);
        } else {
            for (int j = 0; j < 4; ++j) v1[j] = 0u;
        }
        #pragma unroll
        for (int j = 0; j < 8; ++j) {
            const int d = dch * 8 + j;
            const unsigned lo = (v0[j >> 1] >> ((j & 1) * 16)) & 0xffffu;
            const unsigned hi = (v1[j >> 1] >> ((j & 1) * 16)) & 0xffffu;
            *(unsigned*)((char*)Vt + vswz(d, 4 * p)) = lo | (hi << 16);
        }
    }
    __syncthreads();

    // QK^T: wave handles queries [wave*16, +16) x 128 keys (8 col-tiles)
    f32x4 sc[8];
    #pragma unroll
    for (int c = 0; c < 8; ++c)
        #pragma unroll
        for (int j = 0; j < 4; ++j) sc[c][j] = 0.0f;

    bf16x8 aq[2];
    #pragma unroll
    for (int kc = 0; kc < 2; ++kc)
        aq[kc] = *(const bf16x8*)(Qs + (wave * 16 + (lane & 15)) * 72 + kc * 32 + (lane >> 4) * 8);
    #pragma unroll
    for (int c = 0; c < 8; ++c) {
        #pragma unroll
        for (int kc = 0; kc < 2; ++kc) {
            bf16x8 bk_ = *(const bf16x8*)(Ks + (c * 16 + (lane & 15)) * 72 + kc * 32 + (lane >> 4) * 8);
            sc[c] = __builtin_amdgcn_mfma_f32_16x16x32_bf16(aq[kc], bk_, sc[c], 0, 0, 0);
        }
    }

    // masked softmax; acc layout: col = lane&15 (key), row = (lane>>4)*4 + j (query)
    const int grp = lane >> 4, colk = lane & 15;
    float rowmax[4] = {-1e30f, -1e30f, -1e30f, -1e30f};
    #pragma unroll
    for (int c = 0; c < 8; ++c) {
        const int kpos = kstart + c * 16 + colk;
        #pragma unroll
        for (int j = 0; j < 4; ++j) {
            const int qpos = qbase + wave * 16 + grp * 4 + j;
            const int rel = kpos - qpos;
            const bool valid = (kpos >= 0) && (kpos < SEQ) && (rel >= -HALFW) && (rel <= HALFW);
            const float v = valid ? sc[c][j] * 0.125f : -1e30f;
            sc[c][j] = v;
            rowmax[j] = fmaxf(rowmax[j], v);
        }
    }
    #pragma unroll
    for (int j = 0; j < 4; ++j)
        #pragma unroll
        for (int m = 1; m < 16; m <<= 1)
            rowmax[j] = fmaxf(rowmax[j], __shfl_xor(rowmax[j], m, 64));

    float rowsum[4] = {0.f, 0.f, 0.f, 0.f};
    #pragma unroll
    for (int c = 0; c < 8; ++c)
        #pragma unroll
        for (int j = 0; j < 4; ++j) {
            const float p = __expf(sc[c][j] - rowmax[j]);
            sc[c][j] = p;
            rowsum[j] += p;
        }
    #pragma unroll
    for (int j = 0; j < 4; ++j)
        #pragma unroll
        for (int m = 1; m < 16; m <<= 1)
            rowsum[j] += __shfl_xor(rowsum[j], m, 64);

    // write P (bf16) to swizzled LDS for A-fragment re-layout
    #pragma unroll
    for (int c = 0; c < 8; ++c)
        #pragma unroll
        for (int j = 0; j < 4; ++j)
            *(unsigned short*)((char*)Ps + vswz(wave * 16 + grp * 4 + j, (c * 16 + colk) * 2))
                = f2bf(sc[c][j]);
    __syncthreads();

    // PV: P[16x128] @ V[128x64]
    f32x4 o[4];
    #pragma unroll
    for (int n = 0; n < 4; ++n)
        #pragma unroll
        for (int j = 0; j < 4; ++j) o[n][j] = 0.0f;
    #pragma unroll
    for (int kc = 0; kc < 4; ++kc) {
        bf16x8 pa = *(const bf16x8*)((const char*)Ps +
                        vswz(wave * 16 + (lane & 15), kc * 64 + (lane >> 4) * 16));
        #pragma unroll
        for (int n = 0; n < 4; ++n) {
            bf16x8 bv_ = *(const bf16x8*)((const char*)Vt +
                            vswz(n * 16 + (lane & 15), kc * 64 + (lane >> 4) * 16));
            o[n] = __builtin_amdgcn_mfma_f32_16x16x32_bf16(pa, bv_, o[n], 0, 0, 0);
        }
    }

    float rinv[4];
    #pragma unroll
    for (int j = 0; j < 4; ++j) rinv[j] = 1.0f / rowsum[j];
    #pragma unroll
    for (int n = 0; n < 4; ++n)
        #pragma unroll
        for (int j = 0; j < 4; ++j) {
            const int q = qbase + wave * 16 + grp * 4 + j;
            Cb[(size_t)q * D_MODEL + n * 16 + colk] = f2bf(o[n][j] * rinv[j]);
        }
}

// ------------------------------------------------------------------------------
extern "C" void kernel_launch(void* const* d_in, const int* in_sizes, int n_in,
                              void* d_out, int out_size, void* d_ws, size_t ws_size,
                              hipStream_t stream)
{
    (void)in_sizes; (void)n_in; (void)out_size; (void)ws_size;
    const float* x  = (const float*)d_in[0];
    const float* Wq = (const float*)d_in[1];
    const float* bq = (const float*)d_in[2];
    const float* Wk = (const float*)d_in[3];
    const float* bk = (const float*)d_in[4];
    const float* Wv = (const float*)d_in[5];
    const float* bv = (const float*)d_in[6];
    const float* Wo = (const float*)d_in[7];
    const float* bo = (const float*)d_in[8];
    float* out = (float*)d_out;

    char* ws = (char*)d_ws;
    unsigned short* xb  = (unsigned short*)ws;                    // 16.8M elems (33.5MB)
    unsigned short* wqb = (unsigned short*)(ws + 33554432);
    unsigned short* wkb = wqb + 1048576;
    unsigned short* wvb = wkb + 1048576;
    unsigned short* wob = wvb + 1048576;
    unsigned short* qb  = wob + 1048576;
    unsigned short* kb  = qb + (size_t)MROWS * D_MODEL;
    unsigned short* vb  = kb + (size_t)MROWS * D_MODEL;
    unsigned short* ctxb = xb;   // alias: x no longer needed after QKV GEMM

    cvt_f32_bf16<<<dim3(MROWS * D_MODEL / 8 / 256), 256, 0, stream>>>(x, xb, MROWS * D_MODEL / 8);
    cvt4_f32_bf16<<<dim3(D_MODEL * D_MODEL / 8 / 256, 4), 256, 0, stream>>>(
        Wq, Wk, Wv, Wo, wqb, wkb, wvb, wob, D_MODEL * D_MODEL / 8);

    // fused QKV: 128 row-blocks x 24 col-blocks
    gemm_fused<24, 0><<<dim3(128 * 24), 256, 0, stream>>>(
        xb, wqb, wkb, wvb, bq, bk, bv, qb, kb, vb, nullptr);

    attn_band<<<dim3(SEQ / 64, NHEADS, BATCH), 256, 0, stream>>>(qb, kb, vb, ctxb);

    gemm_fused<8, 1><<<dim3(128 * 8), 256, 0, stream>>>(
        ctxb, wob, wob, wob, bo, bo, bo, nullptr, nullptr, nullptr, out);
}

// Round 4
// 245.293 us; speedup vs baseline: 1.2347x; 1.0438x over previous
//
#include <hip/hip_runtime.h>
#include <hip/hip_bf16.h>
#include <cstdint>
#include <cstddef>

#define D_MODEL 1024
#define NHEADS  16
#define HDIM    64
#define HALFW   32
#define BATCH   4
#define SEQ     4096
#define MROWS   (BATCH*SEQ)

typedef __attribute__((ext_vector_type(8))) short        bf16x8;
typedef __attribute__((ext_vector_type(4))) float        f32x4;
typedef __attribute__((ext_vector_type(4))) unsigned int u32x4;

typedef const __attribute__((address_space(1))) void gvoid_t;
typedef __attribute__((address_space(3))) void       lvoid_t;

__device__ __forceinline__ unsigned short f2bf(float f) {
    unsigned int u = __float_as_uint(f);
    u += 0x7fffu + ((u >> 16) & 1u);   // RNE
    return (unsigned short)(u >> 16);
}

// XOR swizzle for row-major [R][128] bf16 LDS tiles (256B rows) - attn kernel.
__device__ __forceinline__ int vswz(int row, int bytecol) {
    return (row * 256 + bytecol) ^ (((row ^ (row >> 3)) & 7) << 4);
}

// ---------------- f32 -> bf16 conversion (vectorized, 8 elems/thread) ----------
__global__ __launch_bounds__(256)
void cvt_f32_bf16(const float* __restrict__ src, unsigned short* __restrict__ dst, int n8) {
    int i = blockIdx.x * 256 + threadIdx.x;
    if (i >= n8) return;
    float4 a = *(const float4*)(src + (size_t)i * 8);
    float4 b = *(const float4*)(src + (size_t)i * 8 + 4);
    u32x4 o;
    o[0] = (unsigned)f2bf(a.x) | ((unsigned)f2bf(a.y) << 16);
    o[1] = (unsigned)f2bf(a.z) | ((unsigned)f2bf(a.w) << 16);
    o[2] = (unsigned)f2bf(b.x) | ((unsigned)f2bf(b.y) << 16);
    o[3] = (unsigned)f2bf(b.z) | ((unsigned)f2bf(b.w) << 16);
    *(u32x4*)(dst + (size_t)i * 8) = o;
}

__global__ __launch_bounds__(256)
void cvt4_f32_bf16(const float* __restrict__ s0, const float* __restrict__ s1,
                   const float* __restrict__ s2, const float* __restrict__ s3,
                   unsigned short* __restrict__ d0, unsigned short* __restrict__ d1,
                   unsigned short* __restrict__ d2, unsigned short* __restrict__ d3, int n8) {
    int i = blockIdx.x * 256 + threadIdx.x;
    if (i >= n8) return;
    const float* src = blockIdx.y == 0 ? s0 : blockIdx.y == 1 ? s1 : blockIdx.y == 2 ? s2 : s3;
    unsigned short* dst = blockIdx.y == 0 ? d0 : blockIdx.y == 1 ? d1 : blockIdx.y == 2 ? d2 : d3;
    float4 a = *(const float4*)(src + (size_t)i * 8);
    float4 b = *(const float4*)(src + (size_t)i * 8 + 4);
    u32x4 o;
    o[0] = (unsigned)f2bf(a.x) | ((unsigned)f2bf(a.y) << 16);
    o[1] = (unsigned)f2bf(a.z) | ((unsigned)f2bf(a.w) << 16);
    o[2] = (unsigned)f2bf(b.x) | ((unsigned)f2bf(b.y) << 16);
    o[3] = (unsigned)f2bf(b.z) | ((unsigned)f2bf(b.w) << 16);
    *(u32x4*)(dst + (size_t)i * 8) = o;
}

// ---------------- 256x256 pipelined bf16 GEMM (B^T), 8 waves, BK=32 ----------
// 4-slot LDS ring; counted vmcnt(8); conflict-free swizzled LDS layout:
//   chunk (row r, k-chunk ks of 8 bf16) stored at byte  r*64 + ((ks^(r&3))<<4)
// Staging: global_load_lds 16B/lane, linear LDS dest, pre-swizzled global src.
template <int NOUT, int F32OUT>
__global__ __launch_bounds__(512)
void gemm256(const unsigned short* __restrict__ A,
             const unsigned short* __restrict__ W0,
             const unsigned short* __restrict__ W1,
             const unsigned short* __restrict__ W2,
             const float* __restrict__ b0, const float* __restrict__ b1,
             const float* __restrict__ b2,
             unsigned short* __restrict__ o0, unsigned short* __restrict__ o1,
             unsigned short* __restrict__ o2, float* __restrict__ of32)
{
    constexpr int K  = 1024;
    constexpr int NT = K / 32;                 // 32 k-tiles
    constexpr int NWG = 64 * 4 * NOUT;
    __shared__ unsigned short lds[65536];      // 4 slots x (A 16KB + B 16KB) = 128KB

    const int tid  = threadIdx.x;
    const int wave = tid >> 6, lane = tid & 63;
    const int wr = wave >> 2, wc = wave & 3;   // 2x4 wave grid; per-wave 128x64

    // bijective XCD swizzle (NWG % 8 == 0); cb fastest within an XCD chunk
    const int bid = blockIdx.x;
    const int g   = (bid & 7) * (NWG / 8) + (bid >> 3);
    const int rb  = g / (4 * NOUT);
    const int cb  = g % (4 * NOUT);
    const int which = cb >> 2;
    const int bm = rb * 256, bn = (cb & 3) * 256;

    const unsigned short* W = (NOUT == 1 || which == 0) ? W0 : (which == 1 ? W1 : W2);
    const float* bias       = (NOUT == 1 || which == 0) ? b0 : (which == 1 ? b1 : b2);
    unsigned short* obf     = (NOUT == 1 || which == 0) ? o0 : (which == 1 ? o1 : o2);

    f32x4 acc[8][4];
    #pragma unroll
    for (int m = 0; m < 8; ++m)
        #pragma unroll
        for (int n = 0; n < 4; ++n)
            #pragma unroll
            for (int j = 0; j < 4; ++j) acc[m][n][j] = 0.0f;

    // staging: per thread 2 chunks per matrix per tile; chunk c = tid (+512)
    const int r0  = tid >> 2;
    const int ks0 = (tid & 3) ^ (r0 & 3);      // (r+128)&3 == r&3, so same for both
    const size_t aoff0 = (size_t)(bm + r0)       * K + ks0 * 8;
    const size_t aoff1 = (size_t)(bm + r0 + 128) * K + ks0 * 8;
    const size_t boff0 = (size_t)(bn + r0)       * K + ks0 * 8;
    const size_t boff1 = (size_t)(bn + r0 + 128) * K + ks0 * 8;
    const int stW = wave * 1024;               // wave-uniform LDS byte base (+lane*16 by HW)

    char* ldsb = (char*)lds;

    auto STAGE_A = [&](int t) {
        const int slot = (t & 3) * 32768;
        const int kt = t * 32;
        __builtin_amdgcn_global_load_lds((gvoid_t*)(A + aoff0 + kt),
            (lvoid_t*)(ldsb + slot + stW), 16, 0, 0);
        __builtin_amdgcn_global_load_lds((gvoid_t*)(A + aoff1 + kt),
            (lvoid_t*)(ldsb + slot + 8192 + stW), 16, 0, 0);
    };
    auto STAGE_B = [&](int t) {
        const int slot = (t & 3) * 32768 + 16384;
        const int kt = t * 32;
        __builtin_amdgcn_global_load_lds((gvoid_t*)(W + boff0 + kt),
            (lvoid_t*)(ldsb + slot + stW), 16, 0, 0);
        __builtin_amdgcn_global_load_lds((gvoid_t*)(W + boff1 + kt),
            (lvoid_t*)(ldsb + slot + 8192 + stW), 16, 0, 0);
    };

    // fragment read bases (conflict-free: banks spread by (ks^lane&3) xor)
    const int lr  = lane & 15;
    const int xb_ = ((lane >> 4) ^ (lane & 3)) << 4;
    const int aread = (wr * 128 + lr) * 64 + xb_;
    const int bread = 16384 + (wc * 64 + lr) * 64 + xb_;

    // prologue: tiles 0..2 staged; wait tile 0 landed (8 = 4 chunks outstanding)
    STAGE_A(0); STAGE_B(0); STAGE_A(1); STAGE_B(1); STAGE_A(2); STAGE_B(2);
    asm volatile("s_waitcnt vmcnt(8)" ::: "memory");
    __builtin_amdgcn_s_barrier();

    for (int t = 0; t < NT; ++t) {
        const char* sl = ldsb + (t & 3) * 32768;
        // ---- phase 1: frags (m 0..3, all n) + stage A(t+3) + MFMA quad 1 ----
        bf16x8 a_lo[4], bfr[4];
        #pragma unroll
        for (int m = 0; m < 4; ++m)
            a_lo[m] = *(const bf16x8*)(sl + aread + m * 1024);
        #pragma unroll
        for (int n = 0; n < 4; ++n)
            bfr[n] = *(const bf16x8*)(sl + bread + n * 1024);
        if (t + 3 < NT) STAGE_A(t + 3);
        __builtin_amdgcn_s_barrier();
        __builtin_amdgcn_s_setprio(1);
        #pragma unroll
        for (int m = 0; m < 4; ++m)
            #pragma unroll
            for (int n = 0; n < 4; ++n)
                acc[m][n] = __builtin_amdgcn_mfma_f32_16x16x32_bf16(a_lo[m], bfr[n], acc[m][n], 0, 0, 0);
        __builtin_amdgcn_s_setprio(0);
        __builtin_amdgcn_s_barrier();
        // ---- phase 2: frags (m 4..7) + stage B(t+3) + vmcnt + MFMA quad 2 ----
        bf16x8 a_hi[4];
        #pragma unroll
        for (int m = 0; m < 4; ++m)
            a_hi[m] = *(const bf16x8*)(sl + aread + 4096 + m * 1024);
        if (t + 3 < NT) STAGE_B(t + 3);
        asm volatile("s_waitcnt vmcnt(8)" ::: "memory");   // tile t+1 fully landed
        __builtin_amdgcn_s_barrier();
        __builtin_amdgcn_s_setprio(1);
        #pragma unroll
        for (int m = 0; m < 4; ++m)
            #pragma unroll
            for (int n = 0; n < 4; ++n)
                acc[m + 4][n] = __builtin_amdgcn_mfma_f32_16x16x32_bf16(a_hi[m], bfr[n], acc[m + 4][n], 0, 0, 0);
        __builtin_amdgcn_s_setprio(0);
        __builtin_amdgcn_s_barrier();
    }

    // epilogue: bias + store
    #pragma unroll
    for (int n = 0; n < 4; ++n) {
        const int col = bn + wc * 64 + n * 16 + lr;
        const float bv = bias[col];
        #pragma unroll
        for (int m = 0; m < 8; ++m) {
            #pragma unroll
            for (int j = 0; j < 4; ++j) {
                const int row = bm + wr * 128 + m * 16 + (lane >> 4) * 4 + j;
                const float v = acc[m][n][j] + bv;
                if (F32OUT) of32[(size_t)row * 1024 + col] = v;
                else        obf[(size_t)row * 1024 + col]  = f2bf(v);
            }
        }
    }
}

// ---------------- banded attention: one block per (b, h, 64-query tile) --------
__global__ __launch_bounds__(256)
void attn_band(const unsigned short* __restrict__ Q,
               const unsigned short* __restrict__ Kk,
               const unsigned short* __restrict__ V,
               unsigned short* __restrict__ Ctx)
{
    __shared__ unsigned short Qs[64 * 72];
    __shared__ unsigned short Ks[128 * 72];
    __shared__ unsigned short Vt[64 * 128];
    __shared__ unsigned short Ps[64 * 128];

    const int qt = blockIdx.x, h = blockIdx.y, b = blockIdx.z;
    const int qbase  = qt * 64;
    const int kstart = qbase - HALFW;
    const int tid = threadIdx.x, wave = tid >> 6, lane = tid & 63;

    const size_t base = (size_t)b * SEQ * D_MODEL + (size_t)h * HDIM;
    const unsigned short* Qb = Q  + base;
    const unsigned short* Kb = Kk + base;
    const unsigned short* Vb = V  + base;
    unsigned short*       Cb = Ctx + base;

    for (int c = tid; c < 512; c += 256) {
        const int row = c >> 3, col = (c & 7) * 8;
        *(u32x4*)(Qs + row * 72 + col) =
            *(const u32x4*)(Qb + (size_t)(qbase + row) * D_MODEL + col);
    }
    for (int c = tid; c < 1024; c += 256) {
        const int krow = c >> 3, col = (c & 7) * 8;
        const int kpos = kstart + krow;
        u32x4 kv;
        if (kpos >= 0 && kpos < SEQ) {
            kv = *(const u32x4*)(Kb + (size_t)kpos * D_MODEL + col);
        } else {
            for (int j = 0; j < 4; ++j) kv[j] = 0u;
        }
        *(u32x4*)(Ks + krow * 72 + col) = kv;
    }
    for (int c = tid; c < 512; c += 256) {
        const int p = c >> 3, dch = c & 7;
        const int k0 = kstart + 2 * p, k1 = k0 + 1;
        u32x4 v0, v1;
        if (k0 >= 0 && k0 < SEQ) {
            v0 = *(const u32x4*)(Vb + (size_t)k0 * D_MODEL + dch * 8);
        } else {
            for (int j = 0; j < 4; ++j) v0[j] = 0u;
        }
        if (k1 >= 0 && k1 < SEQ) {
            v1 = *(const u32x4*)(Vb + (size_t)k1 * D_MODEL + dch * 8);
        } else {
            for (int j = 0; j < 4; ++j) v1[j] = 0u;
        }
        #pragma unroll
        for (int j = 0; j < 8; ++j) {
            const int d = dch * 8 + j;
            const unsigned lo = (v0[j >> 1] >> ((j & 1) * 16)) & 0xffffu;
            const unsigned hi = (v1[j >> 1] >> ((j & 1) * 16)) & 0xffffu;
            *(unsigned*)((char*)Vt + vswz(d, 4 * p)) = lo | (hi << 16);
        }
    }
    __syncthreads();

    f32x4 sc[8];
    #pragma unroll
    for (int c = 0; c < 8; ++c)
        #pragma unroll
        for (int j = 0; j < 4; ++j) sc[c][j] = 0.0f;

    bf16x8 aq[2];
    #pragma unroll
    for (int kc = 0; kc < 2; ++kc)
        aq[kc] = *(const bf16x8*)(Qs + (wave * 16 + (lane & 15)) * 72 + kc * 32 + (lane >> 4) * 8);
    #pragma unroll
    for (int c = 0; c < 8; ++c) {
        #pragma unroll
        for (int kc = 0; kc < 2; ++kc) {
            bf16x8 bk_ = *(const bf16x8*)(Ks + (c * 16 + (lane & 15)) * 72 + kc * 32 + (lane >> 4) * 8);
            sc[c] = __builtin_amdgcn_mfma_f32_16x16x32_bf16(aq[kc], bk_, sc[c], 0, 0, 0);
        }
    }

    const int grp = lane >> 4, colk = lane & 15;
    float rowmax[4] = {-1e30f, -1e30f, -1e30f, -1e30f};
    #pragma unroll
    for (int c = 0; c < 8; ++c) {
        const int kpos = kstart + c * 16 + colk;
        #pragma unroll
        for (int j = 0; j < 4; ++j) {
            const int qpos = qbase + wave * 16 + grp * 4 + j;
            const int rel = kpos - qpos;
            const bool valid = (kpos >= 0) && (kpos < SEQ) && (rel >= -HALFW) && (rel <= HALFW);
            const float v = valid ? sc[c][j] * 0.125f : -1e30f;
            sc[c][j] = v;
            rowmax[j] = fmaxf(rowmax[j], v);
        }
    }
    #pragma unroll
    for (int j = 0; j < 4; ++j)
        #pragma unroll
        for (int m = 1; m < 16; m <<= 1)
            rowmax[j] = fmaxf(rowmax[j], __shfl_xor(rowmax[j], m, 64));

    float rowsum[4] = {0.f, 0.f, 0.f, 0.f};
    #pragma unroll
    for (int c = 0; c < 8; ++c)
        #pragma unroll
        for (int j = 0; j < 4; ++j) {
            const float p = __expf(sc[c][j] - rowmax[j]);
            sc[c][j] = p;
            rowsum[j] += p;
        }
    #pragma unroll
    for (int j = 0; j < 4; ++j)
        #pragma unroll
        for (int m = 1; m < 16; m <<= 1)
            rowsum[j] += __shfl_xor(rowsum[j], m, 64);

    #pragma unroll
    for (int c = 0; c < 8; ++c)
        #pragma unroll
        for (int j = 0; j < 4; ++j)
            *(unsigned short*)((char*)Ps + vswz(wave * 16 + grp * 4 + j, (c * 16 + colk) * 2))
                = f2bf(sc[c][j]);
    __syncthreads();

    f32x4 o[4];
    #pragma unroll
    for (int n = 0; n < 4; ++n)
        #pragma unroll
        for (int j = 0; j < 4; ++j) o[n][j] = 0.0f;
    #pragma unroll
    for (int kc = 0; kc < 4; ++kc) {
        bf16x8 pa = *(const bf16x8*)((const char*)Ps +
                        vswz(wave * 16 + (lane & 15), kc * 64 + (lane >> 4) * 16));
        #pragma unroll
        for (int n = 0; n < 4; ++n) {
            bf16x8 bv_ = *(const bf16x8*)((const char*)Vt +
                            vswz(n * 16 + (lane & 15), kc * 64 + (lane >> 4) * 16));
            o[n] = __builtin_amdgcn_mfma_f32_16x16x32_bf16(pa, bv_, o[n], 0, 0, 0);
        }
    }

    float rinv[4];
    #pragma unroll
    for (int j = 0; j < 4; ++j) rinv[j] = 1.0f / rowsum[j];
    #pragma unroll
    for (int n = 0; n < 4; ++n)
        #pragma unroll
        for (int j = 0; j < 4; ++j) {
            const int q = qbase + wave * 16 + grp * 4 + j;
            Cb[(size_t)q * D_MODEL + n * 16 + colk] = f2bf(o[n][j] * rinv[j]);
        }
}

// ------------------------------------------------------------------------------
extern "C" void kernel_launch(void* const* d_in, const int* in_sizes, int n_in,
                              void* d_out, int out_size, void* d_ws, size_t ws_size,
                              hipStream_t stream)
{
    (void)in_sizes; (void)n_in; (void)out_size; (void)ws_size;
    const float* x  = (const float*)d_in[0];
    const float* Wq = (const float*)d_in[1];
    const float* bq = (const float*)d_in[2];
    const float* Wk = (const float*)d_in[3];
    const float* bk = (const float*)d_in[4];
    const float* Wv = (const float*)d_in[5];
    const float* bv = (const float*)d_in[6];
    const float* Wo = (const float*)d_in[7];
    const float* bo = (const float*)d_in[8];
    float* out = (float*)d_out;

    char* ws = (char*)d_ws;
    unsigned short* xb  = (unsigned short*)ws;
    unsigned short* wqb = (unsigned short*)(ws + 33554432);
    unsigned short* wkb = wqb + 1048576;
    unsigned short* wvb = wkb + 1048576;
    unsigned short* wob = wvb + 1048576;
    unsigned short* qb  = wob + 1048576;
    unsigned short* kb  = qb + (size_t)MROWS * D_MODEL;
    unsigned short* vb  = kb + (size_t)MROWS * D_MODEL;
    unsigned short* ctxb = xb;   // alias: x no longer needed after QKV GEMM

    cvt_f32_bf16<<<dim3(MROWS * D_MODEL / 8 / 256), 256, 0, stream>>>(x, xb, MROWS * D_MODEL / 8);
    cvt4_f32_bf16<<<dim3(D_MODEL * D_MODEL / 8 / 256, 4), 256, 0, stream>>>(
        Wq, Wk, Wv, Wo, wqb, wkb, wvb, wob, D_MODEL * D_MODEL / 8);

    // fused QKV: 64 row-blocks x 12 col-blocks (256^2 tiles)
    gemm256<3, 0><<<dim3(768), 512, 0, stream>>>(
        xb, wqb, wkb, wvb, bq, bk, bv, qb, kb, vb, nullptr);

    attn_band<<<dim3(SEQ / 64, NHEADS, BATCH), 256, 0, stream>>>(qb, kb, vb, ctxb);

    gemm256<1, 1><<<dim3(256), 512, 0, stream>>>(
        ctxb, wob, wob, wob, bo, bo, bo, nullptr, nullptr, nullptr, out);
}

// Round 5
// 232.689 us; speedup vs baseline: 1.3016x; 1.0542x over previous
//
#include <hip/hip_runtime.h>
#include <hip/hip_bf16.h>
#include <cstdint>
#include <cstddef>

#define D_MODEL 1024
#define NHEADS  16
#define HDIM    64
#define HALFW   32
#define BATCH   4
#define SEQ     4096
#define MROWS   (BATCH*SEQ)

typedef __attribute__((ext_vector_type(8))) short        bf16x8;
typedef __attribute__((ext_vector_type(4))) float        f32x4;
typedef __attribute__((ext_vector_type(4))) unsigned int u32x4;

typedef const __attribute__((address_space(1))) void gvoid_t;
typedef __attribute__((address_space(3))) void       lvoid_t;

__device__ __forceinline__ unsigned short f2bf(float f) {
    unsigned int u = __float_as_uint(f);
    u += 0x7fffu + ((u >> 16) & 1u);   // RNE
    return (unsigned short)(u >> 16);
}

// XOR swizzle for row-major [R][128] bf16 LDS tiles (256B rows) - attn kernel.
__device__ __forceinline__ int vswz(int row, int bytecol) {
    return (row * 256 + bytecol) ^ (((row ^ (row >> 3)) & 7) << 4);
}

// ---------------- f32 -> bf16 conversion (vectorized, 8 elems/thread) ----------
__global__ __launch_bounds__(256)
void cvt_f32_bf16(const float* __restrict__ src, unsigned short* __restrict__ dst, int n8) {
    int i = blockIdx.x * 256 + threadIdx.x;
    if (i >= n8) return;
    float4 a = *(const float4*)(src + (size_t)i * 8);
    float4 b = *(const float4*)(src + (size_t)i * 8 + 4);
    u32x4 o;
    o[0] = (unsigned)f2bf(a.x) | ((unsigned)f2bf(a.y) << 16);
    o[1] = (unsigned)f2bf(a.z) | ((unsigned)f2bf(a.w) << 16);
    o[2] = (unsigned)f2bf(b.x) | ((unsigned)f2bf(b.y) << 16);
    o[3] = (unsigned)f2bf(b.z) | ((unsigned)f2bf(b.w) << 16);
    *(u32x4*)(dst + (size_t)i * 8) = o;
}

__global__ __launch_bounds__(256)
void cvt4_f32_bf16(const float* __restrict__ s0, const float* __restrict__ s1,
                   const float* __restrict__ s2, const float* __restrict__ s3,
                   unsigned short* __restrict__ d0, unsigned short* __restrict__ d1,
                   unsigned short* __restrict__ d2, unsigned short* __restrict__ d3, int n8) {
    int i = blockIdx.x * 256 + threadIdx.x;
    if (i >= n8) return;
    const float* src = blockIdx.y == 0 ? s0 : blockIdx.y == 1 ? s1 : blockIdx.y == 2 ? s2 : s3;
    unsigned short* dst = blockIdx.y == 0 ? d0 : blockIdx.y == 1 ? d1 : blockIdx.y == 2 ? d2 : d3;
    float4 a = *(const float4*)(src + (size_t)i * 8);
    float4 b = *(const float4*)(src + (size_t)i * 8 + 4);
    u32x4 o;
    o[0] = (unsigned)f2bf(a.x) | ((unsigned)f2bf(a.y) << 16);
    o[1] = (unsigned)f2bf(a.z) | ((unsigned)f2bf(a.w) << 16);
    o[2] = (unsigned)f2bf(b.x) | ((unsigned)f2bf(b.y) << 16);
    o[3] = (unsigned)f2bf(b.z) | ((unsigned)f2bf(b.w) << 16);
    *(u32x4*)(dst + (size_t)i * 8) = o;
}

// ---------------- 256x256 pipelined bf16 GEMM (B^T), 8 waves, BK=32 ----------
// 4-slot LDS ring; counted vmcnt; conflict-free swizzled LDS layout:
//   16B position p of row r holds k-chunk (p - (r>>1)) & 3
//   -> bank-group(row, chunk g) = (row*4 + ((g + (row>>1))&3)) mod 8 : all 8
//      distinct within each 8-lane cluster of the b128 fragment read.
// Staging: global_load_lds 16B/lane, linear LDS dest, pre-swizzled global src.
template <int NOUT, int F32OUT>
__global__ __launch_bounds__(512)
void gemm256(const unsigned short* __restrict__ A,
             const unsigned short* __restrict__ W0,
             const unsigned short* __restrict__ W1,
             const unsigned short* __restrict__ W2,
             const float* __restrict__ b0, const float* __restrict__ b1,
             const float* __restrict__ b2,
             unsigned short* __restrict__ o0, unsigned short* __restrict__ o1,
             unsigned short* __restrict__ o2, float* __restrict__ of32)
{
    constexpr int K  = 1024;
    constexpr int NT = K / 32;                 // 32 k-tiles
    constexpr int NWG = 64 * 4 * NOUT;
    __shared__ unsigned short lds[65536];      // 4 slots x (A 16KB + B 16KB) = 128KB

    const int tid  = threadIdx.x;
    const int wave = tid >> 6, lane = tid & 63;
    const int wr = wave >> 2, wc = wave & 3;   // 2x4 wave grid; per-wave 128x64

    // bijective XCD swizzle (NWG % 8 == 0); cb fastest within an XCD chunk
    const int bid = blockIdx.x;
    const int g   = (bid & 7) * (NWG / 8) + (bid >> 3);
    const int rb  = g / (4 * NOUT);
    const int cb  = g % (4 * NOUT);
    const int which = cb >> 2;
    const int bm = rb * 256, bn = (cb & 3) * 256;

    const unsigned short* W = (NOUT == 1 || which == 0) ? W0 : (which == 1 ? W1 : W2);
    const float* bias       = (NOUT == 1 || which == 0) ? b0 : (which == 1 ? b1 : b2);
    unsigned short* obf     = (NOUT == 1 || which == 0) ? o0 : (which == 1 ? o1 : o2);

    f32x4 acc[8][4];
    #pragma unroll
    for (int m = 0; m < 8; ++m)
        #pragma unroll
        for (int n = 0; n < 4; ++n)
            #pragma unroll
            for (int j = 0; j < 4; ++j) acc[m][n][j] = 0.0f;

    // staging: per thread 2 chunks per matrix per tile
    const int r0  = tid >> 2;                       // row within 128-half
    const int ks0 = ((tid & 3) - (r0 >> 1)) & 3;    // chunk stored at position tid&3
    const size_t aoff0 = (size_t)(bm + r0)       * K + ks0 * 8;
    const size_t aoff1 = (size_t)(bm + r0 + 128) * K + ks0 * 8;
    const size_t boff0 = (size_t)(bn + r0)       * K + ks0 * 8;
    const size_t boff1 = (size_t)(bn + r0 + 128) * K + ks0 * 8;
    const int stW = wave * 1024;               // wave-uniform LDS byte base (+lane*16 by HW)

    char* ldsb = (char*)lds;

    auto STAGE_A = [&](int t) {
        const int slot = (t & 3) * 32768;
        const int kt = t * 32;
        __builtin_amdgcn_global_load_lds((gvoid_t*)(A + aoff0 + kt),
            (lvoid_t*)(ldsb + slot + stW), 16, 0, 0);
        __builtin_amdgcn_global_load_lds((gvoid_t*)(A + aoff1 + kt),
            (lvoid_t*)(ldsb + slot + 8192 + stW), 16, 0, 0);
    };
    auto STAGE_B = [&](int t) {
        const int slot = (t & 3) * 32768 + 16384;
        const int kt = t * 32;
        __builtin_amdgcn_global_load_lds((gvoid_t*)(W + boff0 + kt),
            (lvoid_t*)(ldsb + slot + stW), 16, 0, 0);
        __builtin_amdgcn_global_load_lds((gvoid_t*)(W + boff1 + kt),
            (lvoid_t*)(ldsb + slot + 8192 + stW), 16, 0, 0);
    };

    // fragment read bases; chunk g = lane>>4 at position ((g + (row>>1))&3)
    const int lr  = lane & 15;
    const int xb_ = (((lane >> 4) + (lr >> 1)) & 3) << 4;
    const int aread = (wr * 128 + lr) * 64 + xb_;
    const int bread = 16384 + (wc * 64 + lr) * 64 + xb_;

    // prologue: tiles 0..2 staged; wait tile 0 landed (8 = 4 chunks outstanding)
    STAGE_A(0); STAGE_B(0); STAGE_A(1); STAGE_B(1); STAGE_A(2); STAGE_B(2);
    asm volatile("s_waitcnt vmcnt(8)" ::: "memory");
    __builtin_amdgcn_s_barrier();

    for (int t = 0; t < NT; ++t) {
        const char* sl = ldsb + (t & 3) * 32768;
        // ---- phase 1: frags (m 0..3, all n) + stage A(t+3) + MFMA quad 1 ----
        bf16x8 a_lo[4], bfr[4];
        #pragma unroll
        for (int m = 0; m < 4; ++m)
            a_lo[m] = *(const bf16x8*)(sl + aread + m * 1024);
        #pragma unroll
        for (int n = 0; n < 4; ++n)
            bfr[n] = *(const bf16x8*)(sl + bread + n * 1024);
        if (t + 3 < NT) STAGE_A(t + 3);
        __builtin_amdgcn_s_barrier();
        __builtin_amdgcn_s_setprio(1);
        #pragma unroll
        for (int m = 0; m < 4; ++m)
            #pragma unroll
            for (int n = 0; n < 4; ++n)
                acc[m][n] = __builtin_amdgcn_mfma_f32_16x16x32_bf16(a_lo[m], bfr[n], acc[m][n], 0, 0, 0);
        __builtin_amdgcn_s_setprio(0);
        __builtin_amdgcn_s_barrier();
        // ---- phase 2: frags (m 4..7) + stage B(t+3) + counted vmcnt + MFMA 2 ----
        bf16x8 a_hi[4];
        #pragma unroll
        for (int m = 0; m < 4; ++m)
            a_hi[m] = *(const bf16x8*)(sl + aread + 4096 + m * 1024);
        if (t + 3 < NT) {
            STAGE_B(t + 3);
            asm volatile("s_waitcnt vmcnt(8)" ::: "memory");   // tile t+1 landed
        } else if (t == NT - 3) {
            asm volatile("s_waitcnt vmcnt(4)" ::: "memory");   // tile NT-2 landed
        } else if (t == NT - 2) {
            asm volatile("s_waitcnt vmcnt(0)" ::: "memory");   // tile NT-1 landed
        }
        __builtin_amdgcn_s_barrier();
        __builtin_amdgcn_s_setprio(1);
        #pragma unroll
        for (int m = 0; m < 4; ++m)
            #pragma unroll
            for (int n = 0; n < 4; ++n)
                acc[m + 4][n] = __builtin_amdgcn_mfma_f32_16x16x32_bf16(a_hi[m], bfr[n], acc[m + 4][n], 0, 0, 0);
        __builtin_amdgcn_s_setprio(0);
        __builtin_amdgcn_s_barrier();
    }

    // epilogue: bias + store, n INNERMOST so each 16-lane group completes a
    // full 128B line in 4 consecutive stores (no partial-line eviction).
    float bvv[4];
    #pragma unroll
    for (int n = 0; n < 4; ++n) bvv[n] = bias[bn + wc * 64 + n * 16 + lr];
    #pragma unroll
    for (int m = 0; m < 8; ++m) {
        #pragma unroll
        for (int j = 0; j < 4; ++j) {
            const int row = bm + wr * 128 + m * 16 + (lane >> 4) * 4 + j;
            #pragma unroll
            for (int n = 0; n < 4; ++n) {
                const int col = bn + wc * 64 + n * 16 + lr;
                const float v = acc[m][n][j] + bvv[n];
                if (F32OUT) of32[(size_t)row * 1024 + col] = v;
                else        obf[(size_t)row * 1024 + col]  = f2bf(v);
            }
        }
    }
}

// ---------------- banded attention: one block per (b, h, 64-query tile) --------
__global__ __launch_bounds__(256)
void attn_band(const unsigned short* __restrict__ Q,
               const unsigned short* __restrict__ Kk,
               const unsigned short* __restrict__ V,
               unsigned short* __restrict__ Ctx)
{
    __shared__ unsigned short Qs[64 * 72];
    __shared__ unsigned short Ks[128 * 72];
    __shared__ unsigned short Vt[64 * 128];
    __shared__ unsigned short Ps[64 * 128];

    const int qt = blockIdx.x, h = blockIdx.y, b = blockIdx.z;
    const int qbase  = qt * 64;
    const int kstart = qbase - HALFW;
    const int tid = threadIdx.x, wave = tid >> 6, lane = tid & 63;

    const size_t base = (size_t)b * SEQ * D_MODEL + (size_t)h * HDIM;
    const unsigned short* Qb = Q  + base;
    const unsigned short* Kb = Kk + base;
    const unsigned short* Vb = V  + base;
    unsigned short*       Cb = Ctx + base;

    for (int c = tid; c < 512; c += 256) {
        const int row = c >> 3, col = (c & 7) * 8;
        *(u32x4*)(Qs + row * 72 + col) =
            *(const u32x4*)(Qb + (size_t)(qbase + row) * D_MODEL + col);
    }
    for (int c = tid; c < 1024; c += 256) {
        const int krow = c >> 3, col = (c & 7) * 8;
        const int kpos = kstart + krow;
        u32x4 kv;
        if (kpos >= 0 && kpos < SEQ) {
            kv = *(const u32x4*)(Kb + (size_t)kpos * D_MODEL + col);
        } else {
            for (int j = 0; j < 4; ++j) kv[j] = 0u;
        }
        *(u32x4*)(Ks + krow * 72 + col) = kv;
    }
    for (int c = tid; c < 512; c += 256) {
        const int p = c >> 3, dch = c & 7;
        const int k0 = kstart + 2 * p, k1 = k0 + 1;
        u32x4 v0, v1;
        if (k0 >= 0 && k0 < SEQ) {
            v0 = *(const u32x4*)(Vb + (size_t)k0 * D_MODEL + dch * 8);
        } else {
            for (int j = 0; j < 4; ++j) v0[j] = 0u;
        }
        if (k1 >= 0 && k1 < SEQ) {
            v1 = *(const u32x4*)(Vb + (size_t)k1 * D_MODEL + dch * 8);
        } else {
            for (int j = 0; j < 4; ++j) v1[j] = 0u;
        }
        #pragma unroll
        for (int j = 0; j < 8; ++j) {
            const int d = dch * 8 + j;
            const unsigned lo = (v0[j >> 1] >> ((j & 1) * 16)) & 0xffffu;
            const unsigned hi = (v1[j >> 1] >> ((j & 1) * 16)) & 0xffffu;
            *(unsigned*)((char*)Vt + vswz(d, 4 * p)) = lo | (hi << 16);
        }
    }
    __syncthreads();

    f32x4 sc[8];
    #pragma unroll
    for (int c = 0; c < 8; ++c)
        #pragma unroll
        for (int j = 0; j < 4; ++j) sc[c][j] = 0.0f;

    bf16x8 aq[2];
    #pragma unroll
    for (int kc = 0; kc < 2; ++kc)
        aq[kc] = *(const bf16x8*)(Qs + (wave * 16 + (lane & 15)) * 72 + kc * 32 + (lane >> 4) * 8);
    #pragma unroll
    for (int c = 0; c < 8; ++c) {
        #pragma unroll
        for (int kc = 0; kc < 2; ++kc) {
            bf16x8 bk_ = *(const bf16x8*)(Ks + (c * 16 + (lane & 15)) * 72 + kc * 32 + (lane >> 4) * 8);
            sc[c] = __builtin_amdgcn_mfma_f32_16x16x32_bf16(aq[kc], bk_, sc[c], 0, 0, 0);
        }
    }

    const int grp = lane >> 4, colk = lane & 15;
    float rowmax[4] = {-1e30f, -1e30f, -1e30f, -1e30f};
    #pragma unroll
    for (int c = 0; c < 8; ++c) {
        const int kpos = kstart + c * 16 + colk;
        #pragma unroll
        for (int j = 0; j < 4; ++j) {
            const int qpos = qbase + wave * 16 + grp * 4 + j;
            const int rel = kpos - qpos;
            const bool valid = (kpos >= 0) && (kpos < SEQ) && (rel >= -HALFW) && (rel <= HALFW);
            const float v = valid ? sc[c][j] * 0.125f : -1e30f;
            sc[c][j] = v;
            rowmax[j] = fmaxf(rowmax[j], v);
        }
    }
    #pragma unroll
    for (int j = 0; j < 4; ++j)
        #pragma unroll
        for (int m = 1; m < 16; m <<= 1)
            rowmax[j] = fmaxf(rowmax[j], __shfl_xor(rowmax[j], m, 64));

    float rowsum[4] = {0.f, 0.f, 0.f, 0.f};
    #pragma unroll
    for (int c = 0; c < 8; ++c)
        #pragma unroll
        for (int j = 0; j < 4; ++j) {
            const float p = __expf(sc[c][j] - rowmax[j]);
            sc[c][j] = p;
            rowsum[j] += p;
        }
    #pragma unroll
    for (int j = 0; j < 4; ++j)
        #pragma unroll
        for (int m = 1; m < 16; m <<= 1)
            rowsum[j] += __shfl_xor(rowsum[j], m, 64);

    #pragma unroll
    for (int c = 0; c < 8; ++c)
        #pragma unroll
        for (int j = 0; j < 4; ++j)
            *(unsigned short*)((char*)Ps + vswz(wave * 16 + grp * 4 + j, (c * 16 + colk) * 2))
                = f2bf(sc[c][j]);
    __syncthreads();

    f32x4 o[4];
    #pragma unroll
    for (int n = 0; n < 4; ++n)
        #pragma unroll
        for (int j = 0; j < 4; ++j) o[n][j] = 0.0f;
    #pragma unroll
    for (int kc = 0; kc < 4; ++kc) {
        bf16x8 pa = *(const bf16x8*)((const char*)Ps +
                        vswz(wave * 16 + (lane & 15), kc * 64 + (lane >> 4) * 16));
        #pragma unroll
        for (int n = 0; n < 4; ++n) {
            bf16x8 bv_ = *(const bf16x8*)((const char*)Vt +
                            vswz(n * 16 + (lane & 15), kc * 64 + (lane >> 4) * 16));
            o[n] = __builtin_amdgcn_mfma_f32_16x16x32_bf16(pa, bv_, o[n], 0, 0, 0);
        }
    }

    float rinv[4];
    #pragma unroll
    for (int j = 0; j < 4; ++j) rinv[j] = 1.0f / rowsum[j];
    #pragma unroll
    for (int n = 0; n < 4; ++n)
        #pragma unroll
        for (int j = 0; j < 4; ++j) {
            const int q = qbase + wave * 16 + grp * 4 + j;
            Cb[(size_t)q * D_MODEL + n * 16 + colk] = f2bf(o[n][j] * rinv[j]);
        }
}

// ------------------------------------------------------------------------------
extern "C" void kernel_launch(void* const* d_in, const int* in_sizes, int n_in,
                              void* d_out, int out_size, void* d_ws, size_t ws_size,
                              hipStream_t stream)
{
    (void)in_sizes; (void)n_in; (void)out_size; (void)ws_size;
    const float* x  = (const float*)d_in[0];
    const float* Wq = (const float*)d_in[1];
    const float* bq = (const float*)d_in[2];
    const float* Wk = (const float*)d_in[3];
    const float* bk = (const float*)d_in[4];
    const float* Wv = (const float*)d_in[5];
    const float* bv = (const float*)d_in[6];
    const float* Wo = (const float*)d_in[7];
    const float* bo = (const float*)d_in[8];
    float* out = (float*)d_out;

    char* ws = (char*)d_ws;
    unsigned short* xb  = (unsigned short*)ws;
    unsigned short* wqb = (unsigned short*)(ws + 33554432);
    unsigned short* wkb = wqb + 1048576;
    unsigned short* wvb = wkb + 1048576;
    unsigned short* wob = wvb + 1048576;
    unsigned short* qb  = wob + 1048576;
    unsigned short* kb  = qb + (size_t)MROWS * D_MODEL;
    unsigned short* vb  = kb + (size_t)MROWS * D_MODEL;
    unsigned short* ctxb = xb;   // alias: x no longer needed after QKV GEMM

    cvt_f32_bf16<<<dim3(MROWS * D_MODEL / 8 / 256), 256, 0, stream>>>(x, xb, MROWS * D_MODEL / 8);
    cvt4_f32_bf16<<<dim3(D_MODEL * D_MODEL / 8 / 256, 4), 256, 0, stream>>>(
        Wq, Wk, Wv, Wo, wqb, wkb, wvb, wob, D_MODEL * D_MODEL / 8);

    // fused QKV: 64 row-blocks x 12 col-blocks (256^2 tiles)
    gemm256<3, 0><<<dim3(768), 512, 0, stream>>>(
        xb, wqb, wkb, wvb, bq, bk, bv, qb, kb, vb, nullptr);

    attn_band<<<dim3(SEQ / 64, NHEADS, BATCH), 256, 0, stream>>>(qb, kb, vb, ctxb);

    gemm256<1, 1><<<dim3(256), 512, 0, stream>>>(
        ctxb, wob, wob, wob, bo, bo, bo, nullptr, nullptr, nullptr, out);
}

// Round 6
// 232.186 us; speedup vs baseline: 1.3044x; 1.0022x over previous
//
#include <hip/hip_runtime.h>
#include <hip/hip_bf16.h>
#include <cstdint>
#include <cstddef>

#define D_MODEL 1024
#define NHEADS  16
#define HDIM    64
#define HALFW   32
#define BATCH   4
#define SEQ     4096
#define MROWS   (BATCH*SEQ)

typedef __attribute__((ext_vector_type(8))) short        bf16x8;
typedef __attribute__((ext_vector_type(4))) float        f32x4;
typedef __attribute__((ext_vector_type(4))) unsigned int u32x4;

typedef const __attribute__((address_space(1))) void gvoid_t;
typedef __attribute__((address_space(3))) void       lvoid_t;

__device__ __forceinline__ unsigned short f2bf(float f) {
    unsigned int u = __float_as_uint(f);
    u += 0x7fffu + ((u >> 16) & 1u);   // RNE
    return (unsigned short)(u >> 16);
}

// XOR swizzle for row-major [R][128] bf16 LDS tiles (256B rows) - attn kernel.
__device__ __forceinline__ int vswz(int row, int bytecol) {
    return (row * 256 + bytecol) ^ (((row ^ (row >> 3)) & 7) << 4);
}

// ---------------- f32 -> bf16 conversion (vectorized, 8 elems/thread) ----------
__global__ __launch_bounds__(256)
void cvt_f32_bf16(const float* __restrict__ src, unsigned short* __restrict__ dst, int n8) {
    int i = blockIdx.x * 256 + threadIdx.x;
    if (i >= n8) return;
    float4 a = *(const float4*)(src + (size_t)i * 8);
    float4 b = *(const float4*)(src + (size_t)i * 8 + 4);
    u32x4 o;
    o[0] = (unsigned)f2bf(a.x) | ((unsigned)f2bf(a.y) << 16);
    o[1] = (unsigned)f2bf(a.z) | ((unsigned)f2bf(a.w) << 16);
    o[2] = (unsigned)f2bf(b.x) | ((unsigned)f2bf(b.y) << 16);
    o[3] = (unsigned)f2bf(b.z) | ((unsigned)f2bf(b.w) << 16);
    *(u32x4*)(dst + (size_t)i * 8) = o;
}

__global__ __launch_bounds__(256)
void cvt4_f32_bf16(const float* __restrict__ s0, const float* __restrict__ s1,
                   const float* __restrict__ s2, const float* __restrict__ s3,
                   unsigned short* __restrict__ d0, unsigned short* __restrict__ d1,
                   unsigned short* __restrict__ d2, unsigned short* __restrict__ d3, int n8) {
    int i = blockIdx.x * 256 + threadIdx.x;
    if (i >= n8) return;
    const float* src = blockIdx.y == 0 ? s0 : blockIdx.y == 1 ? s1 : blockIdx.y == 2 ? s2 : s3;
    unsigned short* dst = blockIdx.y == 0 ? d0 : blockIdx.y == 1 ? d1 : blockIdx.y == 2 ? d2 : d3;
    float4 a = *(const float4*)(src + (size_t)i * 8);
    float4 b = *(const float4*)(src + (size_t)i * 8 + 4);
    u32x4 o;
    o[0] = (unsigned)f2bf(a.x) | ((unsigned)f2bf(a.y) << 16);
    o[1] = (unsigned)f2bf(a.z) | ((unsigned)f2bf(a.w) << 16);
    o[2] = (unsigned)f2bf(b.x) | ((unsigned)f2bf(b.y) << 16);
    o[3] = (unsigned)f2bf(b.z) | ((unsigned)f2bf(b.w) << 16);
    *(u32x4*)(dst + (size_t)i * 8) = o;
}

// ------------- 256x256 8-phase bf16 GEMM (B^T), 8 waves, BK=64 ---------------
// K-half slot ring (4 slots/matrix of 16KB, slot(t,kh)=(2t+kh)&3), per K-tile
// 4 phases: {stage 1 half-tile, ds_read quadrant frags, barrier, setprio,
// 16 MFMA, setprio, [counted vmcnt], barrier}. vmcnt(4) twice per K-tile.
// LDS layout per slot: [256 rows][4 chunks of 16B], chunk c of row r stored at
// position (c+(r>>1))&3  -> 2 lanes/bank-group on b128 frag reads (free).
template <int NOUT, int F32OUT>
__global__ __launch_bounds__(512)
void gemm256(const unsigned short* __restrict__ A,
             const unsigned short* __restrict__ W0,
             const unsigned short* __restrict__ W1,
             const unsigned short* __restrict__ W2,
             const float* __restrict__ b0, const float* __restrict__ b1,
             const float* __restrict__ b2,
             unsigned short* __restrict__ o0, unsigned short* __restrict__ o1,
             unsigned short* __restrict__ o2, float* __restrict__ of32)
{
    constexpr int K  = 1024;
    constexpr int NT = K / 64;                 // 16 K-tiles of 64
    constexpr int NWG = 64 * 4 * NOUT;
    __shared__ unsigned short lds[65536];      // A ring 64KB + B ring 64KB

    const int tid  = threadIdx.x;
    const int wave = tid >> 6, lane = tid & 63;
    const int wr = wave >> 2, wc = wave & 3;   // 2x4 wave grid; per-wave 128x64

    const int bid = blockIdx.x;
    const int g   = (bid & 7) * (NWG / 8) + (bid >> 3);
    const int rb  = g / (4 * NOUT);
    const int cb  = g % (4 * NOUT);
    const int which = cb >> 2;
    const int bm = rb * 256, bn = (cb & 3) * 256;

    const unsigned short* W = (NOUT == 1 || which == 0) ? W0 : (which == 1 ? W1 : W2);
    const float* bias       = (NOUT == 1 || which == 0) ? b0 : (which == 1 ? b1 : b2);
    unsigned short* obf     = (NOUT == 1 || which == 0) ? o0 : (which == 1 ? o1 : o2);

    f32x4 acc[8][4];
    #pragma unroll
    for (int m = 0; m < 8; ++m)
        #pragma unroll
        for (int n = 0; n < 4; ++n)
            #pragma unroll
            for (int j = 0; j < 4; ++j) acc[m][n][j] = 0.0f;

    char* ldsb = (char*)lds;

    // staging addresses: half-tile (16KB) = 2 loads x 512 thr x 16B
    const int idx0 = tid, idx1 = tid + 512;
    const int r0 = idx0 >> 2, r1 = idx1 >> 2;
    const int c0 = ((idx0 & 3) - (r0 >> 1)) & 3;
    const int c1 = ((idx1 & 3) - (r1 >> 1)) & 3;
    const size_t sA0 = (size_t)(bm + r0) * K + c0 * 8;
    const size_t sA1 = (size_t)(bm + r1) * K + c1 * 8;
    const size_t sB0 = (size_t)(bn + r0) * K + c0 * 8;
    const size_t sB1 = (size_t)(bn + r1) * K + c1 * 8;
    const int ldsW = wave * 1024;              // wave-uniform base (+lane*16 by HW)

    auto STAGE = [&](int t, int kh, int isA) {
        const int slot = ((t << 1) + kh) & 3;
        const int base = (isA ? 0 : 65536) + slot * 16384 + ldsW;
        const int ke = t * 64 + kh * 32;
        const unsigned short* M = isA ? A : W;
        const size_t s0 = isA ? sA0 : sB0;
        const size_t s1 = isA ? sA1 : sB1;
        __builtin_amdgcn_global_load_lds((gvoid_t*)(M + s0 + ke),
            (lvoid_t*)(ldsb + base), 16, 0, 0);
        __builtin_amdgcn_global_load_lds((gvoid_t*)(M + s1 + ke),
            (lvoid_t*)(ldsb + base + 8192), 16, 0, 0);
    };

    // fragment read bases
    const int lr = lane & 15;
    const int pp = (((lane >> 4) + (lr >> 1)) & 3) << 4;       // swizzled chunk pos
    const int abase = (wr * 128 + lr) * 64 + pp;               // + slot*16384 + mi*1024
    const int bbase = 65536 + (wc * 64 + lr) * 64 + pp;        // + slot*16384 + ni*1024

    // prologue: stage tile 0 fully; wait kh0 landed (4 newest = kh1 pair)
    STAGE(0, 0, 1); STAGE(0, 0, 0); STAGE(0, 1, 1); STAGE(0, 1, 0);
    asm volatile("s_waitcnt vmcnt(4)" ::: "memory");
    __builtin_amdgcn_s_barrier();

    #pragma unroll 1
    for (int t = 0; t < NT; ++t) {
        const int more = (t + 1 < NT);
        // ---------------- phase 0: kc0, n0-1 ----------------
        {
            const int so = (((t << 1) + 0) & 3) * 16384;
            if (more) STAGE(t + 1, 0, 1);
            bf16x8 a[8], b2_[2];
            #pragma unroll
            for (int m = 0; m < 8; ++m) a[m] = *(const bf16x8*)(ldsb + so + abase + m * 1024);
            #pragma unroll
            for (int n = 0; n < 2; ++n) b2_[n] = *(const bf16x8*)(ldsb + so + bbase + n * 1024);
            __builtin_amdgcn_s_barrier();
            __builtin_amdgcn_s_setprio(1);
            #pragma unroll
            for (int m = 0; m < 8; ++m)
                #pragma unroll
                for (int n = 0; n < 2; ++n)
                    acc[m][n] = __builtin_amdgcn_mfma_f32_16x16x32_bf16(a[m], b2_[n], acc[m][n], 0, 0, 0);
            __builtin_amdgcn_s_setprio(0);
            __builtin_amdgcn_s_barrier();
            // ---------------- phase 1: kc0, n2-3 ----------------
            if (more) STAGE(t + 1, 0, 0);
            #pragma unroll
            for (int n = 0; n < 2; ++n) b2_[n] = *(const bf16x8*)(ldsb + so + bbase + (n + 2) * 1024);
            __builtin_amdgcn_s_barrier();
            __builtin_amdgcn_s_setprio(1);
            #pragma unroll
            for (int m = 0; m < 8; ++m)
                #pragma unroll
                for (int n = 0; n < 2; ++n)
                    acc[m][n + 2] = __builtin_amdgcn_mfma_f32_16x16x32_bf16(a[m], b2_[n], acc[m][n + 2], 0, 0, 0);
            __builtin_amdgcn_s_setprio(0);
            if (more) { asm volatile("s_waitcnt vmcnt(4)" ::: "memory"); }
            else      { asm volatile("s_waitcnt vmcnt(0)" ::: "memory"); }
            __builtin_amdgcn_s_barrier();
        }
        // ---------------- phase 2: kc1, n0-1 ----------------
        {
            const int so = (((t << 1) + 1) & 3) * 16384;
            if (more) STAGE(t + 1, 1, 1);
            bf16x8 a[8], b2_[2];
            #pragma unroll
            for (int m = 0; m < 8; ++m) a[m] = *(const bf16x8*)(ldsb + so + abase + m * 1024);
            #pragma unroll
            for (int n = 0; n < 2; ++n) b2_[n] = *(const bf16x8*)(ldsb + so + bbase + n * 1024);
            __builtin_amdgcn_s_barrier();
            __builtin_amdgcn_s_setprio(1);
            #pragma unroll
            for (int m = 0; m < 8; ++m)
                #pragma unroll
                for (int n = 0; n < 2; ++n)
                    acc[m][n] = __builtin_amdgcn_mfma_f32_16x16x32_bf16(a[m], b2_[n], acc[m][n], 0, 0, 0);
            __builtin_amdgcn_s_setprio(0);
            __builtin_amdgcn_s_barrier();
            // ---------------- phase 3: kc1, n2-3 ----------------
            if (more) STAGE(t + 1, 1, 0);
            #pragma unroll
            for (int n = 0; n < 2; ++n) b2_[n] = *(const bf16x8*)(ldsb + so + bbase + (n + 2) * 1024);
            __builtin_amdgcn_s_barrier();
            __builtin_amdgcn_s_setprio(1);
            #pragma unroll
            for (int m = 0; m < 8; ++m)
                #pragma unroll
                for (int n = 0; n < 2; ++n)
                    acc[m][n + 2] = __builtin_amdgcn_mfma_f32_16x16x32_bf16(a[m], b2_[n], acc[m][n + 2], 0, 0, 0);
            __builtin_amdgcn_s_setprio(0);
            if (t + 2 < NT) { asm volatile("s_waitcnt vmcnt(4)" ::: "memory"); }
            else            { asm volatile("s_waitcnt vmcnt(0)" ::: "memory"); }
            __builtin_amdgcn_s_barrier();
        }
    }

    // epilogue: bias + store, n innermost (full 128B lines per 16-lane group)
    float bvv[4];
    #pragma unroll
    for (int n = 0; n < 4; ++n) bvv[n] = bias[bn + wc * 64 + n * 16 + lr];
    #pragma unroll
    for (int m = 0; m < 8; ++m) {
        #pragma unroll
        for (int j = 0; j < 4; ++j) {
            const int row = bm + wr * 128 + m * 16 + (lane >> 4) * 4 + j;
            #pragma unroll
            for (int n = 0; n < 4; ++n) {
                const int col = bn + wc * 64 + n * 16 + lr;
                const float v = acc[m][n][j] + bvv[n];
                if (F32OUT) of32[(size_t)row * 1024 + col] = v;
                else        obf[(size_t)row * 1024 + col]  = f2bf(v);
            }
        }
    }
}

// ---------------- banded attention: one block per (b, h, 64-query tile) --------
__global__ __launch_bounds__(256)
void attn_band(const unsigned short* __restrict__ Q,
               const unsigned short* __restrict__ Kk,
               const unsigned short* __restrict__ V,
               unsigned short* __restrict__ Ctx)
{
    __shared__ unsigned short Qs[64 * 72];
    __shared__ unsigned short Ks[128 * 72];
    __shared__ unsigned short Vt[64 * 128];
    __shared__ unsigned short Ps[64 * 128];

    const int qt = blockIdx.x, h = blockIdx.y, b = blockIdx.z;
    const int qbase  = qt * 64;
    const int kstart = qbase - HALFW;
    const int tid = threadIdx.x, wave = tid >> 6, lane = tid & 63;

    const size_t base = (size_t)b * SEQ * D_MODEL + (size_t)h * HDIM;
    const unsigned short* Qb = Q  + base;
    const unsigned short* Kb = Kk + base;
    const unsigned short* Vb = V  + base;
    unsigned short*       Cb = Ctx + base;

    for (int c = tid; c < 512; c += 256) {
        const int row = c >> 3, col = (c & 7) * 8;
        *(u32x4*)(Qs + row * 72 + col) =
            *(const u32x4*)(Qb + (size_t)(qbase + row) * D_MODEL + col);
    }
    for (int c = tid; c < 1024; c += 256) {
        const int krow = c >> 3, col = (c & 7) * 8;
        const int kpos = kstart + krow;
        u32x4 kv;
        if (kpos >= 0 && kpos < SEQ) {
            kv = *(const u32x4*)(Kb + (size_t)kpos * D_MODEL + col);
        } else {
            for (int j = 0; j < 4; ++j) kv[j] = 0u;
        }
        *(u32x4*)(Ks + krow * 72 + col) = kv;
    }
    for (int c = tid; c < 512; c += 256) {
        const int p = c >> 3, dch = c & 7;
        const int k0 = kstart + 2 * p, k1 = k0 + 1;
        u32x4 v0, v1;
        if (k0 >= 0 && k0 < SEQ) {
            v0 = *(const u32x4*)(Vb + (size_t)k0 * D_MODEL + dch * 8);
        } else {
            for (int j = 0; j < 4; ++j) v0[j] = 0u;
        }
        if (k1 >= 0 && k1 < SEQ) {
            v1 = *(const u32x4*)(Vb + (size_t)k1 * D_MODEL + dch * 8);
        } else {
            for (int j = 0; j < 4; ++j) v1[j] = 0u;
        }
        #pragma unroll
        for (int j = 0; j < 8; ++j) {
            const int d = dch * 8 + j;
            const unsigned lo = (v0[j >> 1] >> ((j & 1) * 16)) & 0xffffu;
            const unsigned hi = (v1[j >> 1] >> ((j & 1) * 16)) & 0xffffu;
            *(unsigned*)((char*)Vt + vswz(d, 4 * p)) = lo | (hi << 16);
        }
    }
    __syncthreads();

    f32x4 sc[8];
    #pragma unroll
    for (int c = 0; c < 8; ++c)
        #pragma unroll
        for (int j = 0; j < 4; ++j) sc[c][j] = 0.0f;

    bf16x8 aq[2];
    #pragma unroll
    for (int kc = 0; kc < 2; ++kc)
        aq[kc] = *(const bf16x8*)(Qs + (wave * 16 + (lane & 15)) * 72 + kc * 32 + (lane >> 4) * 8);
    #pragma unroll
    for (int c = 0; c < 8; ++c) {
        #pragma unroll
        for (int kc = 0; kc < 2; ++kc) {
            bf16x8 bk_ = *(const bf16x8*)(Ks + (c * 16 + (lane & 15)) * 72 + kc * 32 + (lane >> 4) * 8);
            sc[c] = __builtin_amdgcn_mfma_f32_16x16x32_bf16(aq[kc], bk_, sc[c], 0, 0, 0);
        }
    }

    const int grp = lane >> 4, colk = lane & 15;
    float rowmax[4] = {-1e30f, -1e30f, -1e30f, -1e30f};
    #pragma unroll
    for (int c = 0; c < 8; ++c) {
        const int kpos = kstart + c * 16 + colk;
        #pragma unroll
        for (int j = 0; j < 4; ++j) {
            const int qpos = qbase + wave * 16 + grp * 4 + j;
            const int rel = kpos - qpos;
            const bool valid = (kpos >= 0) && (kpos < SEQ) && (rel >= -HALFW) && (rel <= HALFW);
            const float v = valid ? sc[c][j] * 0.125f : -1e30f;
            sc[c][j] = v;
            rowmax[j] = fmaxf(rowmax[j], v);
        }
    }
    #pragma unroll
    for (int j = 0; j < 4; ++j)
        #pragma unroll
        for (int m = 1; m < 16; m <<= 1)
            rowmax[j] = fmaxf(rowmax[j], __shfl_xor(rowmax[j], m, 64));

    float rowsum[4] = {0.f, 0.f, 0.f, 0.f};
    #pragma unroll
    for (int c = 0; c < 8; ++c)
        #pragma unroll
        for (int j = 0; j < 4; ++j) {
            const float p = __expf(sc[c][j] - rowmax[j]);
            sc[c][j] = p;
            rowsum[j] += p;
        }
    #pragma unroll
    for (int j = 0; j < 4; ++j)
        #pragma unroll
        for (int m = 1; m < 16; m <<= 1)
            rowsum[j] += __shfl_xor(rowsum[j], m, 64);

    #pragma unroll
    for (int c = 0; c < 8; ++c)
        #pragma unroll
        for (int j = 0; j < 4; ++j)
            *(unsigned short*)((char*)Ps + vswz(wave * 16 + grp * 4 + j, (c * 16 + colk) * 2))
                = f2bf(sc[c][j]);
    __syncthreads();

    f32x4 o[4];
    #pragma unroll
    for (int n = 0; n < 4; ++n)
        #pragma unroll
        for (int j = 0; j < 4; ++j) o[n][j] = 0.0f;
    #pragma unroll
    for (int kc = 0; kc < 4; ++kc) {
        bf16x8 pa = *(const bf16x8*)((const char*)Ps +
                        vswz(wave * 16 + (lane & 15), kc * 64 + (lane >> 4) * 16));
        #pragma unroll
        for (int n = 0; n < 4; ++n) {
            bf16x8 bv_ = *(const bf16x8*)((const char*)Vt +
                            vswz(n * 16 + (lane & 15), kc * 64 + (lane >> 4) * 16));
            o[n] = __builtin_amdgcn_mfma_f32_16x16x32_bf16(pa, bv_, o[n], 0, 0, 0);
        }
    }

    float rinv[4];
    #pragma unroll
    for (int j = 0; j < 4; ++j) rinv[j] = 1.0f / rowsum[j];
    #pragma unroll
    for (int n = 0; n < 4; ++n)
        #pragma unroll
        for (int j = 0; j < 4; ++j) {
            const int q = qbase + wave * 16 + grp * 4 + j;
            Cb[(size_t)q * D_MODEL + n * 16 + colk] = f2bf(o[n][j] * rinv[j]);
        }
}

// ------------------------------------------------------------------------------
extern "C" void kernel_launch(void* const* d_in, const int* in_sizes, int n_in,
                              void* d_out, int out_size, void* d_ws, size_t ws_size,
                              hipStream_t stream)
{
    (void)in_sizes; (void)n_in; (void)out_size; (void)ws_size;
    const float* x  = (const float*)d_in[0];
    const float* Wq = (const float*)d_in[1];
    const float* bq = (const float*)d_in[2];
    const float* Wk = (const float*)d_in[3];
    const float* bk = (const float*)d_in[4];
    const float* Wv = (const float*)d_in[5];
    const float* bv = (const float*)d_in[6];
    const float* Wo = (const float*)d_in[7];
    const float* bo = (const float*)d_in[8];
    float* out = (float*)d_out;

    char* ws = (char*)d_ws;
    unsigned short* xb  = (unsigned short*)ws;
    unsigned short* wqb = (unsigned short*)(ws + 33554432);
    unsigned short* wkb = wqb + 1048576;
    unsigned short* wvb = wkb + 1048576;
    unsigned short* wob = wvb + 1048576;
    unsigned short* qb  = wob + 1048576;
    unsigned short* kb  = qb + (size_t)MROWS * D_MODEL;
    unsigned short* vb  = kb + (size_t)MROWS * D_MODEL;
    unsigned short* ctxb = xb;   // alias: x no longer needed after QKV GEMM

    cvt_f32_bf16<<<dim3(MROWS * D_MODEL / 8 / 256), 256, 0, stream>>>(x, xb, MROWS * D_MODEL / 8);
    cvt4_f32_bf16<<<dim3(D_MODEL * D_MODEL / 8 / 256, 4), 256, 0, stream>>>(
        Wq, Wk, Wv, Wo, wqb, wkb, wvb, wob, D_MODEL * D_MODEL / 8);

    // fused QKV: 64 row-blocks x 12 col-blocks (256^2 tiles)
    gemm256<3, 0><<<dim3(768), 512, 0, stream>>>(
        xb, wqb, wkb, wvb, bq, bk, bv, qb, kb, vb, nullptr);

    attn_band<<<dim3(SEQ / 64, NHEADS, BATCH), 256, 0, stream>>>(qb, kb, vb, ctxb);

    gemm256<1, 1><<<dim3(256), 512, 0, stream>>>(
        ctxb, wob, wob, wob, bo, bo, bo, nullptr, nullptr, nullptr, out);
}